// Round 15
// baseline (95.399 us; speedup 1.0000x reference)
//
#include <hip/hip_runtime.h>

#define CIN   256
#define COUT  256
#define HH    64
#define WW    64
#define KD    2304         // CIN * 9
#define NPIX  16384        // B * HO * WO
#define SPLIT 16
#define CPS   (CIN / SPLIT)
#define NSTEP 36           // K per half = 1152 = 36 x 32

typedef __attribute__((ext_vector_type(4))) float  float4v;
typedef __attribute__((ext_vector_type(4))) unsigned int uint4v;
typedef _Float16 h2 __attribute__((ext_vector_type(2)));
typedef _Float16 h8 __attribute__((ext_vector_type(8)));
typedef unsigned int u32;
typedef unsigned short u16;

__device__ __forceinline__ h2 as_h2(u32 v) { union { u32 u; h2 h; } x; x.u = v; return x.h; }
__device__ __forceinline__ u32 as_u32(h2 h) { union { u32 u; h2 h; } x; x.h = h; return x.u; }
__device__ __forceinline__ u16 f2h_bits(float f) { _Float16 h = (_Float16)f; return *(u16*)&h; }
__device__ __forceinline__ u32 packh2(float a, float b) {
  h2 h; h[0] = (_Float16)a; h[1] = (_Float16)b; return as_u32(h);
}

__device__ __forceinline__ void gload_lds16(const void* g, void* l) {
  __builtin_amdgcn_global_load_lds((const __attribute__((address_space(1))) u32*)g,
                                   (__attribute__((address_space(3))) u32*)l, 16, 0, 0);
}

// ---------------- Kernel 1a: offset/mask partials (f16-packed), split x16 ----------------
__global__ __launch_bounds__(256) void offmask_part_kernel(
    const float* __restrict__ x,
    const float* __restrict__ off_dw, const float* __restrict__ off_pw,
    const float* __restrict__ mask_dw, const float* __restrict__ mask_pw,
    u32* __restrict__ part2)
{
  int m = blockIdx.x * 256 + threadIdx.x;
  int s = blockIdx.y;
  int b = m >> 12, pix = m & 4095;
  int ho = pix >> 6, wo = pix & 63;
  const float* xb = x + (size_t)b * CIN * 4096;

  float acc[27];
#pragma unroll
  for (int j = 0; j < 27; ++j) acc[j] = 0.f;

  int c0 = s * CPS;
  for (int ci = 0; ci < CPS; ++ci) {
    int c = c0 + ci;
    const float* xc = xb + (size_t)c * 4096;
    float d_off = 0.f, d_msk = 0.f;
#pragma unroll
    for (int t = 0; t < 9; ++t) {
      int gy = ho + t / 3 - 1, gx = wo + t % 3 - 1;
      bool ok = (gy >= 0) & (gy < HH) & (gx >= 0) & (gx < WW);
      float v = ok ? xc[gy * 64 + gx] : 0.f;
      d_off += v * off_dw[c * 9 + t];
      d_msk += v * mask_dw[c * 9 + t];
    }
#pragma unroll
    for (int j = 0; j < 18; ++j) acc[j] += d_off * off_pw[j * 256 + c];
#pragma unroll
    for (int j = 0; j < 9; ++j) acc[18 + j] += d_msk * mask_pw[j * 256 + c];
  }
  uint4v o[4];
#pragma unroll
  for (int k = 0; k < 13; ++k) o[k >> 2][k & 3] = packh2(acc[2 * k], acc[2 * k + 1]);
  o[3][1] = packh2(acc[26], 0.f);
  o[3][2] = 0; o[3][3] = 0;
  uint4v* pp = (uint4v*)(part2 + ((size_t)s * NPIX + m) * 16);
#pragma unroll
  for (int q = 0; q < 4; ++q) pp[q] = o[q];
}

// ---------------- Kernel 1b: reduce f16 partials -> rec f32 ----------------
__global__ __launch_bounds__(256) void offmask_reduce_kernel(
    const u32* __restrict__ part2, float* __restrict__ rec)
{
  int i = blockIdx.x * 256 + threadIdx.x;   // over NPIX*16
  int m = i >> 4, k = i & 15;
  int j0 = 2 * k, j1 = 2 * k + 1;
  if (j0 >= 27) { rec[(size_t)m * 32 + j0] = 0.f; rec[(size_t)m * 32 + j1] = 0.f; return; }
  float s0 = 0.f, s1 = 0.f;
#pragma unroll
  for (int s = 0; s < SPLIT; ++s) {
    h2 v = as_h2(part2[((size_t)s * NPIX + m) * 16 + k]);
    s0 += (float)v[0]; s1 += (float)v[1];
  }
  rec[(size_t)m * 32 + j0] = (j0 < 18) ? s0 : 2.f / (1.f + __expf(-s0));
  rec[(size_t)m * 32 + j1] = (j1 < 18) ? s1 : ((j1 < 27) ? 2.f / (1.f + __expf(-s1)) : 0.f);
}

// ---------------- Kernel 2: weight f32 -> f16 [co][kk*256 + c] ----------------
__global__ __launch_bounds__(256) void wconv_kernel(const float* __restrict__ w,
                                                    u16* __restrict__ wb)
{
  int i = blockIdx.x * 256 + threadIdx.x;
  int co = i / KD, rem = i - co * KD;
  int c = rem / 9, kk = rem - c * 9;
  wb[co * KD + kk * 256 + c] = f2h_bits(w[i]);
}

// ---------------- Kernel 2b: x NCHW f32 -> xt NHWC f16 ----------------
__global__ __launch_bounds__(256) void xpose_kernel(const float* __restrict__ x,
                                                    u16* __restrict__ xt)
{
  __shared__ float t[64][65];
  int ptile = blockIdx.x;
  int ctile = blockIdx.y;
  int b     = blockIdx.z;
  int tid = threadIdx.x;
  const float* xb = x + (size_t)b * CIN * 4096 + (size_t)ctile * 64 * 4096 + ptile * 64;
#pragma unroll
  for (int i = 0; i < 16; ++i) {
    int c = i * 4 + (tid >> 6), p = tid & 63;
    t[c][p] = xb[(size_t)c * 4096 + p];
  }
  __syncthreads();
  u16* xo = xt + ((size_t)b * 4096 + ptile * 64) * 256 + ctile * 64;
#pragma unroll
  for (int i = 0; i < 16; ++i) {
    int p = i * 4 + (tid >> 6), c = tid & 63;
    xo[(size_t)p * 256 + c] = f2h_bits(t[c][p]);
  }
}

// ---------------- Kernel 4: FUSED im2col+GEMM, PRODUCER-CONSUMER waves ----------------
// Block = 512 thr: waves 0-3 PRODUCERS (sample+blend B -> LDS, DMA A, counted
// vmcnt), waves 4-7 CONSUMERS (ds_read + MFMA only, no VMEM). m114: MFMA-wave
// and VALU-wave co-schedule fully -> barrier interval = max(roles), not sum.
// Tile 256cout x 128px, K-split x2 (K=1152, 36 steps of 32). Grid 256 = 1/CU.
// LDS: A 3x16KB (2-deep DMA prefetch) + B 2x8KB = 64KB.
// Producer ledger/step: enter with A(t+1)[4]; issue S(t+1)[8]+A(t+2)[4];
// vmcnt(4) drains S(t+1)+A(t+1), keeps A(t+2); BLEND->lB[(t+1)&1]; lgkm(0);
// s_barrier. Consumer/step: 12 ds_read + 32 MFMA; lgkm(0)+fence; s_barrier.
// Barrier counts: both paths 37 (1 prologue + 36 loop). Swizzle as R9-R14.
__global__ __launch_bounds__(512, 2) void gemm_fused_kernel(
    const u16* __restrict__ A,     // wb f16 [COUT][KD]
    const u16* __restrict__ xt,    // NHWC f16 [B*4096][256]
    const float* __restrict__ rec, // [NPIX][32]
    u16* __restrict__ tmp2)        // [2][B][COUT][4096] f16 partials
{
  __shared__ __align__(16) u16 lA[3][256 * 32];   // 3 x 16 KB
  __shared__ __align__(16) u16 lB[2][128 * 32];   // 2 x 8 KB
  const int tid = threadIdx.x;
  const int ord = blockIdx.x;            // 0..255
  const int xcd = ord & 7, slot = ord >> 3;
  const int ptile = (slot >> 1) * 8 + xcd;   // 0..127 (bijective)
  const int h     = slot & 1;                // K half
  const int m0  = ptile * 128;
  const int b_img = ptile >> 5;          // 32 ptiles per image
  const int cbase = h * 128;
  const int wave = tid >> 6, lane = tid & 63;

#define KCOL(t_) (((t_) >> 2) * 256 + cbase + ((t_) & 3) * 32)

  if (wave < 4) {
    // ====================== PRODUCER ======================
    const int p = tid;                   // 0..255
    // A staging: 4 chunks; instruction q covers chunk block (wave*4+q)*64
    u32 aDst[4]; const u16* aSrc[4];
#pragma unroll
    for (int q = 0; q < 4; ++q) {
      int g = (wave * 4 + q) * 64 + lane;        // chunk id 0..1023
      int row = g >> 2, sub = g & 3;
      int ko = (sub ^ (row & 3) ^ ((row >> 2) & 3)) * 8;
      aSrc[q] = A + (size_t)row * KD + ko;
      aDst[q] = g * 8;                           // u16 offset = base_q + lane*8
    }
    // B sampling: px 0..127, 16 ch per thread
    const int px_t = p >> 1;
    const int chh  = (p & 1) * 16;
    const int m_px = m0 + px_t;
    const int ho = (m_px & 4095) >> 6, wo = m_px & 63;
    const float* rp = rec + (size_t)m_px * 32;
    const u16* xb = xt + (size_t)b_img * 4096 * 256;
    const int swzp = (px_t & 3) ^ ((px_t >> 2) & 3);
    const int wAddr0 = px_t * 32 + ((((p & 1) * 2)     ^ swzp) * 8);
    const int wAddr1 = px_t * 32 + ((((p & 1) * 2 + 1) ^ swzp) * 8);

    u32 cOff[4];
    h2  wh[4];

#define CALC_CORNERS(kk_) do {                                             \
    float dy = rp[(kk_) * 2], dx = rp[(kk_) * 2 + 1], msk = rp[18 + (kk_)];\
    float py  = (float)(ho - 1 + ((kk_) / 3)) + dy;                        \
    float pxf = (float)(wo - 1 + ((kk_) % 3)) + dx;                        \
    float fy = floorf(py), fx = floorf(pxf);                               \
    int y0 = (int)fy, x0 = (int)fx;                                        \
    float wy1 = py - fy, wy0 = 1.f - wy1;                                  \
    float wx1 = pxf - fx, wx0 = 1.f - wx1;                                 \
    _Pragma("unroll")                                                      \
    for (int cr = 0; cr < 4; ++cr) {                                       \
      int iy = y0 + (cr >> 1), ix = x0 + (cr & 1);                         \
      bool valid = (iy >= 0) & (iy < HH) & (ix >= 0) & (ix < WW);          \
      int iyc = min(max(iy, 0), HH - 1), ixc = min(max(ix, 0), WW - 1);    \
      cOff[cr] = (u32)(iyc * 64 + ixc) * 256;                              \
      float wy = (cr >> 1) ? wy1 : wy0;                                    \
      float wx = (cr & 1) ? wx1 : wx0;                                     \
      float wf = valid ? (wy * wx * msk) : 0.f;                            \
      _Float16 hw = (_Float16)wf;                                          \
      wh[cr] = (h2){hw, hw};                                               \
    }                                                                      \
  } while (0)

#define STAGE_A4(k_, slot_) do {                                           \
    int k0_ = KCOL(k_);                                                    \
    _Pragma("unroll")                                                      \
    for (int q = 0; q < 4; ++q)                                            \
      gload_lds16(aSrc[q] + k0_, lA[slot_] + aDst[q]);                     \
  } while (0)

#define SAMP_LOAD(t_, va, vb) do {                                         \
    int c0n_ = cbase + ((t_) & 3) * 32 + chh;                              \
    _Pragma("unroll")                                                      \
    for (int cr = 0; cr < 4; ++cr) {                                       \
      va[cr] = *(const uint4v*)(xb + cOff[cr] + c0n_);                     \
      vb[cr] = *(const uint4v*)(xb + cOff[cr] + c0n_ + 8);                 \
    }                                                                      \
  } while (0)

#define BLEND_WRITE(bufi_, va, vb) do {                                    \
    uint4v o0, o1;                                                         \
    _Pragma("unroll")                                                      \
    for (int w_ = 0; w_ < 4; ++w_) {                                       \
      h2 s0_ = wh[0] * as_h2(va[0][w_]) + wh[1] * as_h2(va[1][w_]);        \
      s0_   += wh[2] * as_h2(va[2][w_]) + wh[3] * as_h2(va[3][w_]);        \
      h2 s1_ = wh[0] * as_h2(vb[0][w_]) + wh[1] * as_h2(vb[1][w_]);        \
      s1_   += wh[2] * as_h2(vb[2][w_]) + wh[3] * as_h2(vb[3][w_]);        \
      o0[w_] = as_u32(s0_); o1[w_] = as_u32(s1_);                          \
    }                                                                      \
    *(uint4v*)&lB[bufi_][wAddr0] = o0;                                     \
    *(uint4v*)&lB[bufi_][wAddr1] = o1;                                     \
  } while (0)

    // ---- prologue: S(0)[8] -> A(0)[4] -> A(1)[4]; vmcnt(4) keeps A(1) ----
    {
      CALC_CORNERS(0);
      uint4v va[4], vb[4];
      SAMP_LOAD(0, va, vb);
      STAGE_A4(0, 0);
      STAGE_A4(1, 1);
      asm volatile("s_waitcnt vmcnt(4)" ::: "memory");
      BLEND_WRITE(0, va, vb);
      asm volatile("s_waitcnt lgkmcnt(0)" ::: "memory");
      __builtin_amdgcn_s_barrier();
    }
    for (int it = 0; it < 6; ++it) {
#pragma unroll
      for (int u = 0; u < 6; ++u) {
        const int t = it * 6 + u;
        const int tn  = (t + 1 == NSTEP) ? 0 : t + 1;
        const int tn2 = (t + 2 >= NSTEP) ? (t + 2 - NSTEP) : t + 2;
        if ((tn & 3) == 0) CALC_CORNERS(tn >> 2);
        uint4v va[4], vb[4];
        SAMP_LOAD(tn, va, vb);                 // +8
        STAGE_A4(tn2, (t + 2) % 3);            // +4
        asm volatile("s_waitcnt vmcnt(4)" ::: "memory");  // keep A(t+2)
        BLEND_WRITE((t + 1) & 1, va, vb);
        asm volatile("s_waitcnt lgkmcnt(0)" ::: "memory");
        __builtin_amdgcn_s_barrier();
      }
    }
#undef CALC_CORNERS
#undef STAGE_A4
#undef SAMP_LOAD
#undef BLEND_WRITE
  } else {
    // ====================== CONSUMER ======================
    const int cw = wave - 4;               // 0..3
    const int wm = cw >> 1, wn = cw & 1;   // cout-half(128) x px-half(64)
    const int rl = lane & 15, kq = lane >> 4;
    const int sA = (kq ^ (rl & 3) ^ ((rl >> 2) & 3)) * 8;

    float4v acc[8][4];
#pragma unroll
    for (int m = 0; m < 8; ++m)
#pragma unroll
      for (int n = 0; n < 4; ++n) acc[m][n] = float4v{0.f, 0.f, 0.f, 0.f};

    __builtin_amdgcn_s_barrier();          // matches producer prologue barrier
    for (int it = 0; it < 6; ++it) {
#pragma unroll
      for (int u = 0; u < 6; ++u) {
        const int t = it * 6 + u;
        h8 af[8], bf[4];
#pragma unroll
        for (int m = 0; m < 8; ++m)
          af[m] = *(const h8*)&lA[t % 3][(wm * 128 + m * 16 + rl) * 32 + sA];
#pragma unroll
        for (int n = 0; n < 4; ++n)
          bf[n] = *(const h8*)&lB[t & 1][(wn * 64 + n * 16 + rl) * 32 + sA];
#pragma unroll
        for (int m = 0; m < 8; ++m)
#pragma unroll
          for (int n = 0; n < 4; ++n)
            acc[m][n] = __builtin_amdgcn_mfma_f32_16x16x32_f16(af[m], bf[n], acc[m][n], 0, 0, 0);
        asm volatile("s_waitcnt lgkmcnt(0)" ::: "memory");
        __builtin_amdgcn_s_barrier();
      }
    }
    // epilogue: write f16 partial half-tile (no barriers)
    const int p_base = (m0 & 4095) + wn * 64;
    u16* db = tmp2 + (size_t)h * COUT * NPIX + (size_t)b_img * COUT * 4096;
#pragma unroll
    for (int m = 0; m < 8; ++m) {
#pragma unroll
      for (int j = 0; j < 4; ++j) {
        int co = wm * 128 + m * 16 + kq * 4 + j;
#pragma unroll
        for (int n = 0; n < 4; ++n) {
          int pp = p_base + n * 16 + rl;
          db[(size_t)co * 4096 + pp] = f2h_bits(acc[m][n][j]);
        }
      }
    }
  }
#undef KCOL
}

// ---------------- Kernel 5: out = bias + sum of 2 f16 half-tiles ----------------
__global__ __launch_bounds__(256) void add_kernel(const u16* __restrict__ tmp2,
                                                  const float* __restrict__ bias,
                                                  float* __restrict__ out)
{
  size_t i = ((size_t)blockIdx.x * 256 + threadIdx.x) * 8;  // over COUT*NPIX
  int co = (int)((i >> 12) & 255);
  float bv = bias[co];
  uint4v v0 = *(const uint4v*)(tmp2 + i);
  uint4v v1 = *(const uint4v*)(tmp2 + (size_t)COUT * NPIX + i);
  float4v oA, oB;
#pragma unroll
  for (int w = 0; w < 4; ++w) {
    h2 a = as_h2(v0[w]), b = as_h2(v1[w]);
    float lo = (float)a[0] + (float)b[0] + bv;
    float hi = (float)a[1] + (float)b[1] + bv;
    if (w < 2) { oA[w * 2] = lo; oA[w * 2 + 1] = hi; }
    else       { oB[(w - 2) * 2] = lo; oB[(w - 2) * 2 + 1] = hi; }
  }
  *(float4v*)(out + i) = oA;
  *(float4v*)(out + i + 4) = oB;
}

extern "C" void kernel_launch(void* const* d_in, const int* in_sizes, int n_in,
                              void* d_out, int out_size, void* d_ws, size_t ws_size,
                              hipStream_t stream) {
  const float* x       = (const float*)d_in[0];
  const float* weight  = (const float*)d_in[1];
  const float* bias    = (const float*)d_in[2];
  const float* off_dw  = (const float*)d_in[3];
  const float* off_pw  = (const float*)d_in[4];
  const float* mask_dw = (const float*)d_in[5];
  const float* mask_pw = (const float*)d_in[6];

  // ws layout: rec 2MB @0 | wb 1.18MB @2,097,152 | xt 8.39MB @3,276,800 |
  //            @11,665,408: part2 16.78MB (consumed by reduce), then tmp2
  //            16.78MB aliases it (written by gemm after reduce).
  //            total = 28,442,624 B
  if (ws_size < 28442624ull) return;
  float* rec   = (float*)d_ws;
  u16*   wb    = (u16*)((char*)d_ws + 2097152);
  u16*   xt    = (u16*)((char*)d_ws + 3276800);
  u32*   part2 = (u32*)((char*)d_ws + 11665408);
  u16*   tmp2  = (u16*)((char*)d_ws + 11665408);
  float* out   = (float*)d_out;

  wconv_kernel<<<dim3(2304), dim3(256), 0, stream>>>(weight, wb);
  offmask_part_kernel<<<dim3(NPIX / 256, SPLIT), dim3(256), 0, stream>>>(
      x, off_dw, off_pw, mask_dw, mask_pw, part2);
  offmask_reduce_kernel<<<dim3(NPIX * 16 / 256), dim3(256), 0, stream>>>(part2, rec);
  xpose_kernel<<<dim3(64, 4, 4), dim3(256), 0, stream>>>(x, xt);
  gemm_fused_kernel<<<dim3(256), dim3(512), 0, stream>>>(wb, xt, rec, tmp2);
  add_kernel<<<dim3(COUT * NPIX / 8 / 256), dim3(256), 0, stream>>>(tmp2, bias, out);
}